// Round 4
// baseline (232.589 us; speedup 1.0000x reference)
//
#include <hip/hip_runtime.h>
#include <math.h>

// Problem constants
static constexpr int NB  = 8;      // batch
static constexpr int NRC = 4096;   // rec atoms
static constexpr int NKP = 20;     // keypoints
static constexpr int NF  = 256;    // features
static constexpr int NHD = 4;      // heads
static constexpr int NKH = NKP * NHD;  // 80 fused (k,h)
static constexpr int KCL = 8;      // k-closest
static constexpr int NT  = 16;     // row tiles in K3 (4096/256)
static constexpr float SCALE = 0.0625f; // 1/sqrt(256)

// workspace layout (float offsets)
// WT [1024][256] at 0  (dead after k12; P aliases it)
// M  [8][80][256] at 262144
static constexpr int WT_OFF = 0;
static constexpr int M_OFF  = 262144;
static constexpr int P_OFF  = 0;   // P [8][16][80][4] = 40960 floats, aliases WT

// K0: WT[c][f] = W[f][c]   (W is [256 f][1024 c]); 128 blocks, 32f x 64c tiles
__global__ __launch_bounds__(256) void k0_transpose(const float* __restrict__ W,
                                                    float* __restrict__ WT) {
    __shared__ float tile[32][65];
    int c0 = (blockIdx.x & 15) * 64;
    int f0 = (blockIdx.x >> 4) * 32;
    int lx = threadIdx.x & 63, ly = threadIdx.x >> 6;
#pragma unroll
    for (int rr = 0; rr < 8; ++rr) {
        int fr = ly + rr * 4;
        tile[fr][lx] = W[(f0 + fr) * 1024 + c0 + lx];
    }
    __syncthreads();
    int lf = threadIdx.x & 31, cy = threadIdx.x >> 5;
#pragma unroll
    for (int rr = 0; rr < 8; ++rr) {
        int cr = cy + rr * 8;
        WT[(c0 + cr) * 256 + f0 + lf] = tile[lf][cr];
    }
}

// K12: fused ft_dst + M.  One block per (b, k); 512 threads.
// phase1: ft[c] = sum_g h0[b,k,g] * W[g,c]  for c = tid, tid+512 (coalesced W)
// phase2: M[b, k*4+h, f] = SCALE * sum_d WT[(h*256+d)*256+f] * ft[h*256+d]
//         thread = (h = tid>>8 handling h and h+2, f = tid&255)  (coalesced WT)
__global__ __launch_bounds__(512) void k12_m(const float* __restrict__ h0,
                                             const float* __restrict__ W,
                                             const float* __restrict__ WT,
                                             float* __restrict__ M) {
    int bx = blockIdx.x;            // 160
    int b = bx / NKP, k = bx % NKP;
    int tid = threadIdx.x;
    __shared__ float h0l[NF];
    __shared__ float ftl[1024];
    if (tid < NF) h0l[tid] = h0[(b * NKP + k) * NF + tid];
    __syncthreads();
    {
        float a0 = 0.f, a1 = 0.f;
        const float* wp = W + tid;
#pragma unroll 4
        for (int g = 0; g < NF; ++g) {
            float hg = h0l[g];
            a0 += hg * wp[g * 1024];
            a1 += hg * wp[g * 1024 + 512];
        }
        ftl[tid] = a0;
        ftl[tid + 512] = a1;
    }
    __syncthreads();
    {
        int f = tid & 255, h = tid >> 8;   // h in {0,1}, also handles h+2
        float a0 = 0.f, a1 = 0.f;
        const float* wt0 = WT + (h * 256) * 256 + f;
        const float* wt1 = WT + ((h + 2) * 256) * 256 + f;
        const float* f0p = ftl + h * 256;
        const float* f1p = ftl + (h + 2) * 256;
#pragma unroll 4
        for (int d = 0; d < 256; ++d) {
            a0 += f0p[d] * wt0[d * 256];
            a1 += f1p[d] * wt1[d * 256];
        }
        M[((size_t)b * NKH + k * NHD + h) * NF + f]     = a0 * SCALE;
        M[((size_t)b * NKH + k * NHD + h + 2) * NF + f] = a1 * SCALE;
    }
}

// K3: scores + exp + weighted partial sums.
// M kept in natural [kh][f] layout in LDS; each block handles 40 of the 80
// kh-columns (40 KB static LDS). grid 256 = (b, 16 row-tiles, 2 col-halves).
// 512 threads = 8 waves; wave w owns 5 cols, lane owns 4 rows.
// M reads are full-wave same-address float4 broadcasts (conflict-free).
__global__ __launch_bounds__(512) void k3_scores(const float* __restrict__ hrec,
                                                 const float* __restrict__ xrec,
                                                 const float* __restrict__ Mg,
                                                 float* __restrict__ P) {
    __shared__ float Ml[40 * 256];  // 40 KB
    int bx = blockIdx.x;
    int b = bx >> 5;
    int rem = bx & 31;
    int t = rem >> 1;
    int g = rem & 1;
    int tid = threadIdx.x;

    const float4* Mg4 = (const float4*)(Mg + ((size_t)b * NKH + g * 40) * NF);
    float4* Ml4 = (float4*)Ml;
#pragma unroll
    for (int i = 0; i < 5; ++i)
        Ml4[i * 512 + tid] = Mg4[i * 512 + tid];
    __syncthreads();

    int w = tid >> 6, lane = tid & 63;
    int c0 = w * 5;                    // within this half
    int r0 = t * 256 + lane * 4;

    float acc[5][4];
#pragma unroll
    for (int c = 0; c < 5; ++c)
#pragma unroll
        for (int r = 0; r < 4; ++r) acc[c][r] = 0.f;

    const float4* A = (const float4*)(hrec + ((size_t)b * NRC + r0) * NF);
    const float* Mlc = Ml + c0 * NF;

#pragma unroll 2
    for (int f4 = 0; f4 < 64; ++f4) {
        float4 a0 = A[f4];
        float4 a1 = A[64 + f4];
        float4 a2 = A[128 + f4];
        float4 a3 = A[192 + f4];
#pragma unroll
        for (int c = 0; c < 5; ++c) {
            float4 m = *(const float4*)(Mlc + c * NF + f4 * 4);
            acc[c][0] += a0.x * m.x + a0.y * m.y + a0.z * m.z + a0.w * m.w;
            acc[c][1] += a1.x * m.x + a1.y * m.y + a1.z * m.z + a1.w * m.w;
            acc[c][2] += a2.x * m.x + a2.y * m.y + a2.z * m.z + a2.w * m.w;
            acc[c][3] += a3.x * m.x + a3.y * m.y + a3.z * m.z + a3.w * m.w;
        }
    }

    // positions for the 4 rows: 12 consecutive floats, float4-aligned
    const float4* X = (const float4*)(xrec + ((size_t)b * NRC + r0) * 3);
    float4 x0 = X[0], x1 = X[1], x2 = X[2];
    float xs[4] = {x0.x, x0.w, x1.z, x2.y};
    float ys[4] = {x0.y, x1.x, x1.w, x2.z};
    float zs[4] = {x0.z, x1.y, x2.x, x2.w};

    float* Pp = P + ((size_t)(b * NT + t) * NKH + g * 40 + c0) * 4;
#pragma unroll
    for (int c = 0; c < 5; ++c) {
        float e0 = __expf(acc[c][0]), e1 = __expf(acc[c][1]);
        float e2 = __expf(acc[c][2]), e3 = __expf(acc[c][3]);
        float s0 = e0 + e1 + e2 + e3;
        float s1 = e0 * xs[0] + e1 * xs[1] + e2 * xs[2] + e3 * xs[3];
        float s2 = e0 * ys[0] + e1 * ys[1] + e2 * ys[2] + e3 * ys[3];
        float s3 = e0 * zs[0] + e1 * zs[1] + e2 * zs[2] + e3 * zs[3];
#pragma unroll
        for (int m = 1; m < 64; m <<= 1) {
            s0 += __shfl_xor(s0, m, 64);
            s1 += __shfl_xor(s1, m, 64);
            s2 += __shfl_xor(s2, m, 64);
            s3 += __shfl_xor(s3, m, 64);
        }
        if (lane == 0) {
            Pp[c * 4 + 0] = s0; Pp[c * 4 + 1] = s1;
            Pp[c * 4 + 2] = s2; Pp[c * 4 + 3] = s3;
        }
    }
}

#define CSWAP(i, j)                                                         \
    if (d[j] < d[i] || (d[j] == d[i] && ix[j] < ix[i])) {                   \
        float td = d[i]; d[i] = d[j]; d[j] = td;                            \
        int ti = ix[i]; ix[i] = ix[j]; ix[j] = ti;                          \
    }

// K4: per (b,k): kp_pos, top-8 via sorted register queues, knn mean, MLP, LN.
// grid 160 blocks, 512 threads (8 waves).
__global__ __launch_bounds__(512) void k4_final(const float* __restrict__ hrec,
                                                const float* __restrict__ xrec,
                                                const float* __restrict__ P,
                                                const float* __restrict__ Wm,
                                                const float* __restrict__ bm,
                                                const float* __restrict__ gam,
                                                const float* __restrict__ bet,
                                                float* __restrict__ out) {
    int bx = blockIdx.x;
    int b = bx / NKP, k = bx % NKP;
    int tid = threadIdx.x;
    int w = tid >> 6, lane = tid & 63;

    __shared__ float Sh[16];
    __shared__ float posl[4];
    __shared__ float redv[8];
    __shared__ int   redi[8];
    __shared__ int   kidxs[KCL];
    __shared__ float fin[NF + KCL];
    __shared__ float part[2][NF];
    __shared__ float wred[8][2];
    __shared__ float stat[2];

    // phase 0: kp_pos from P
    if (tid < 16) {
        int h = tid >> 2, s = tid & 3;
        float a = 0.f;
#pragma unroll
        for (int t = 0; t < NT; ++t)
            a += P[((b * NT + t) * NKH + k * NHD + h) * 4 + s];
        Sh[tid] = a;
    }
    __syncthreads();
    if (tid == 0) {
#pragma unroll
        for (int c = 0; c < 3; ++c) {
            float p = 0.f;
#pragma unroll
            for (int h = 0; h < NHD; ++h) p += Sh[h * 4 + c + 1] / Sh[h * 4];
            p *= 0.25f;
            posl[c] = p;
            out[(b * NKP + k) * 3 + c] = p;
        }
    }
    __syncthreads();

    // phase 1: d2 for 8 atoms/thread, sorted register queue
    float px = posl[0], py = posl[1], pz = posl[2];
    float d[8];
    int ix[8];
#pragma unroll
    for (int s = 0; s < 8; ++s) {
        int i = s * 512 + tid;
        const float* x = xrec + ((size_t)b * NRC + i) * 3;
        float dx = x[0] - px, dy = x[1] - py, dz = x[2] - pz;
        d[s] = dx * dx + dy * dy + dz * dz;
        ix[s] = i;
    }
    // Batcher odd-even merge sort, 8 elements, ascending by (d, idx)
    CSWAP(0, 1) CSWAP(2, 3) CSWAP(4, 5) CSWAP(6, 7)
    CSWAP(0, 2) CSWAP(1, 3) CSWAP(4, 6) CSWAP(5, 7)
    CSWAP(1, 2) CSWAP(5, 6)
    CSWAP(0, 4) CSWAP(1, 5) CSWAP(2, 6) CSWAP(3, 7)
    CSWAP(2, 4) CSWAP(3, 5)
    CSWAP(1, 2) CSWAP(3, 4) CSWAP(5, 6)

    // phase 2: 8 extraction rounds
    for (int j = 0; j < KCL; ++j) {
        float bd = d[0];
        int bi = ix[0];
#pragma unroll
        for (int m = 1; m < 64; m <<= 1) {
            float od = __shfl_xor(bd, m, 64);
            int oi = __shfl_xor(bi, m, 64);
            if (od < bd || (od == bd && oi < bi)) { bd = od; bi = oi; }
        }
        if (lane == 0) { redv[w] = bd; redi[w] = bi; }
        __syncthreads();
        bd = redv[0]; bi = redi[0];
#pragma unroll
        for (int q = 1; q < 8; ++q) {
            float od = redv[q]; int oi = redi[q];
            if (od < bd || (od == bd && oi < bi)) { bd = od; bi = oi; }
        }
        if (tid == 0) { kidxs[j] = bi; fin[NF + j] = sqrtf(bd); }
        if (ix[0] == bi) {  // pop my head
#pragma unroll
            for (int s = 0; s < 7; ++s) { d[s] = d[s + 1]; ix[s] = ix[s + 1]; }
            d[7] = 3.4e38f; ix[7] = 0x7fffffff;
        }
        __syncthreads();
    }

    // phase 3: knn feature mean
    if (tid < NF) {
        float hm = 0.f;
#pragma unroll
        for (int j = 0; j < KCL; ++j)
            hm += hrec[((size_t)b * NRC + kidxs[j]) * NF + tid];
        fin[tid] = hm * 0.125f;
    }
    __syncthreads();

    // phase 4: MLP 264 -> 256, split 2 ways over input dim
    {
        int o = tid & 255, p = tid >> 8;
        float acc = 0.f;
        const float* wp = Wm + o;
#pragma unroll 2
        for (int i = p * 132; i < p * 132 + 132; ++i)
            acc += fin[i] * wp[i * NF];
        part[p][o] = acc;
    }
    __syncthreads();

    float v = 0.f;
    if (tid < NF) {
        float psum = bm[tid] + part[0][tid] + part[1][tid];
        v = psum / (1.f + __expf(-psum));
    }
    // phase 5: LayerNorm (zeros from tid>=256 don't affect sums)
    float s = v, sq = v * v;
#pragma unroll
    for (int m = 1; m < 64; m <<= 1) {
        s += __shfl_xor(s, m, 64);
        sq += __shfl_xor(sq, m, 64);
    }
    if (lane == 0) { wred[w][0] = s; wred[w][1] = sq; }
    __syncthreads();
    if (tid == 0) {
        float ts = 0.f, tq = 0.f;
#pragma unroll
        for (int q = 0; q < 8; ++q) { ts += wred[q][0]; tq += wred[q][1]; }
        float mu = ts / 256.f;
        float var = tq / 256.f - mu * mu;
        stat[0] = mu;
        stat[1] = rsqrtf(var + 1e-5f);
    }
    __syncthreads();
    if (tid < NF) {
        float o = (v - stat[0]) * stat[1] * gam[tid] + bet[tid];
        out[NB * NKP * 3 + (b * NKP + k) * NF + tid] = o;
    }
}

extern "C" void kernel_launch(void* const* d_in, const int* in_sizes, int n_in,
                              void* d_out, int out_size, void* d_ws, size_t ws_size,
                              hipStream_t stream) {
    const float* h_rec = (const float*)d_in[0];
    const float* x_rec = (const float*)d_in[1];
    const float* h0_kp = (const float*)d_in[2];
    const float* W_src = (const float*)d_in[3];
    const float* W_mlp = (const float*)d_in[4];
    const float* b_mlp = (const float*)d_in[5];
    const float* gam   = (const float*)d_in[6];
    const float* bet   = (const float*)d_in[7];
    float* outp = (float*)d_out;
    float* ws = (float*)d_ws;

    float* WT = ws + WT_OFF;
    float* M  = ws + M_OFF;
    float* P  = ws + P_OFF;   // aliases WT (dead after k12)

    hipLaunchKernelGGL(k0_transpose, dim3(128), dim3(256), 0, stream, W_src, WT);
    hipLaunchKernelGGL(k12_m, dim3(160), dim3(512), 0, stream, h0_kp, W_src, WT, M);
    hipLaunchKernelGGL(k3_scores, dim3(256), dim3(512), 0, stream,
                       h_rec, x_rec, M, P);
    hipLaunchKernelGGL(k4_final, dim3(160), dim3(512), 0, stream,
                       h_rec, x_rec, P, W_mlp, b_mlp, gam, bet, outp);
}